// Round 9
// baseline (506.141 us; speedup 1.0000x reference)
//
#include <hip/hip_runtime.h>
#include <stdint.h>

typedef int v4i  __attribute__((ext_vector_type(4)));
typedef int v16i __attribute__((ext_vector_type(16)));

#define M_TOK 8192
#define N_OUT 4096
#define K_IN  4096
#define KT_N  (K_IN / 32)          // 128 fragment columns

#define BM 256
#define BN 256

// -------------------------------------------------------------------------
// R9: NO-LDS GEMM. Five scheduling structures (R3 barrier-removal, R5
// register pipeline, R6/R7 2-blocks/CU, R8 sched_group_barrier interleave)
// all measured the same ~2660-2710 cyc/tile == MFMA demand (1171) + LDS
// demand (~1500): on this op mix the LDS pipe and MFMA issue serialize at
// the wave/CU level regardless of schedule. So: eliminate LDS. Pack A,B
// into FRAGMENT-MAJOR layout (each 32x32 i8 MFMA fragment = 1 KB
// contiguous, lane-major), so every operand load is one coalesced
// global_load_dwordx4 to registers. No LDS, no barriers, no waitcnt asm --
// compiler emits counted vmcnt for the register double-buffer. Reuse is
// caught by L1 (16 KB/k-step working set per CU) and per-XCD L2 (block
// swizzle kept). Per-SIMD: 16 MFMA x 36.6 cyc + 12 load issues per K-32
// step -> ~650 cyc even if fully serial = ~70 us GEMM.
// Counter experiment: SQ_LDS_BANK_CONFLICT must drop 1.26e7 -> ~0.
//
// Fragment layout: frag(rt, kt) = 1 KB at ((rt*KT_N + kt) << 10);
// byte lane*16 holds row rt*32 + (lane&31), k = kt*32 + (lane>>5)*16 .. +15
// == exactly the mfma_i32_32x32x32_i8 A/B operand mapping.
// -------------------------------------------------------------------------

// ---- pack + relayout: thread handles 16 consecutive k of one row =
// 64 B coalesced read, one 16 B fragment-lane write.
__device__ __forceinline__ int pack4(int4 a) {
    return (a.x & 255) | ((a.y & 255) << 8) | ((a.z & 255) << 16) | ((a.w & 255) << 24);
}

__global__ __launch_bounds__(256) void pack_frag(
    const int4* __restrict__ x, const int4* __restrict__ w,
    int* __restrict__ dA, int* __restrict__ dB, int ntA, int ntB)
{
    int i = blockIdx.x * blockDim.x + threadIdx.x;
    const int4* src; int* dst; int r, k0;
    if (i < ntA) {
        src = x; dst = dA;
        r  = i >> 8;                 // row (K/16 = 256 threads per row)
        k0 = (i & 255) << 4;         // first k of this thread's 16
    } else {
        int j = i - ntA;
        if (j >= ntB) return;
        src = w; dst = dB;
        r  = j >> 8;
        k0 = (j & 255) << 4;
    }
    // read 16 int32 carriers (4 x int4, 64 B contiguous)
    const int4* p = src + ((size_t)r * K_IN + k0) / 4;
    int4 c0 = p[0], c1 = p[1], c2 = p[2], c3 = p[3];
    // fragment-major dest: frag(r>>5, k0>>5), lane = (r&31) + 32*((k0>>4)&1)
    const int kt   = k0 >> 5;
    const int lane = (r & 31) + (((k0 >> 4) & 1) << 5);
    int* q = dst + ((((size_t)(r >> 5) * KT_N + kt) << 8) + (lane << 2));
    q[0] = pack4(c0); q[1] = pack4(c1); q[2] = pack4(c2); q[3] = pack4(c3);
}

// -------------------------------------------------------------------------
// GEMM: 256x256 block, 8 waves (2Mx4N), wave = 128x64 as 4x2 of
// mfma_i32_32x32x32_i8. Register double-buffer (sets s0/s1), depth-2
// prefetch, zero LDS, zero barriers.
// -------------------------------------------------------------------------
__global__ __launch_bounds__(512, 2) void gemm_i8_kernel(
    const char* __restrict__ A8,      // fragment-major [M/32][KT_N][1KB]
    const char* __restrict__ B8,      // fragment-major [N/32][KT_N][1KB]
    const float* __restrict__ scale_ptr,
    float* __restrict__ out)          // [M][N] float + 1 scalar at end
{
    const int tid  = threadIdx.x;
    const int wave = tid >> 6;        // 0..7
    const int lane = tid & 63;

    // ---- bijective XCD swizzle of the 512-block grid (512 % 8 == 0).
    int wg = (blockIdx.x & 7) * 64 + (blockIdx.x >> 3);
    const int bx = wg >> 5;           // 0..15 (N tiles)
    const int by = wg & 31;           // 0..31 (M tiles)
    const int bm = by * BM;
    const int bn = bx * BN;

    const int wr = wave >> 2;         // 0..1
    const int wc = wave & 3;          // 0..3
    const int wm = wr * 128;          // wave row offset in tile
    const int wn = wc * 64;           // wave col offset in tile

    v16i acc[4][2];
#pragma unroll
    for (int mi = 0; mi < 4; ++mi)
#pragma unroll
        for (int nj = 0; nj < 2; ++nj)
#pragma unroll
            for (int r = 0; r < 16; ++r)
                acc[mi][nj][r] = 0;

    // ---- per-frag base pointers (include lane*16)
    const char* pA[4]; const char* pB[2];
#pragma unroll
    for (int mi = 0; mi < 4; ++mi)
        pA[mi] = A8 + (((size_t)((bm + wm) / 32 + mi) * KT_N) << 10) + lane * 16;
#pragma unroll
    for (int nj = 0; nj < 2; ++nj)
        pB[nj] = B8 + (((size_t)((bn + wn) / 32 + nj) * KT_N) << 10) + lane * 16;

#define LOADSET(av, bv, kt) do {                                             \
        const int _o = (kt) << 10;                                           \
        _Pragma("unroll")                                                    \
        for (int _m = 0; _m < 4; ++_m) av[_m] = *(const v4i*)(pA[_m] + _o);  \
        _Pragma("unroll")                                                    \
        for (int _n = 0; _n < 2; ++_n) bv[_n] = *(const v4i*)(pB[_n] + _o);  \
    } while (0)

    // ---- prologue: sets for kt=0,1 in flight
    v4i a0[4], b0[2], a1[4], b1[2];
    LOADSET(a0, b0, 0);
    LOADSET(a1, b1, 1);

    // ---- main loop: 64 iterations, 2 k-steps each. Compiler emits counted
    // vmcnt before each MFMA cluster (wait set resident, next set in
    // flight); WAR on the set registers orders reload after last consume.
    for (int kt = 0; kt < KT_N; kt += 2) {
#pragma unroll
        for (int mi = 0; mi < 4; ++mi)
#pragma unroll
            for (int nj = 0; nj < 2; ++nj)
                acc[mi][nj] = __builtin_amdgcn_mfma_i32_32x32x32_i8(
                    a0[mi], b0[nj], acc[mi][nj], 0, 0, 0);
        const int nk0 = (kt + 2 < KT_N) ? kt + 2 : KT_N - 2;   // clamp: dead values
        LOADSET(a0, b0, nk0);

#pragma unroll
        for (int mi = 0; mi < 4; ++mi)
#pragma unroll
            for (int nj = 0; nj < 2; ++nj)
                acc[mi][nj] = __builtin_amdgcn_mfma_i32_32x32x32_i8(
                    a1[mi], b1[nj], acc[mi][nj], 0, 0, 0);
        const int nk1 = (kt + 3 < KT_N) ? kt + 3 : KT_N - 1;   // clamp: dead values
        LOADSET(a1, b1, nk1);
    }
#undef LOADSET

    // ---- epilogue: y = clip(rint(acc * scale), -128, 127) as float
    // 32x32 C/D layout: col = lane&31, row = (reg&3) + 8*(reg>>2) + 4*(lane>>5)
    const int fm = lane & 31;
    const int fh = lane >> 5;
    const float s     = scale_ptr[0];
    const float scale = (s * 0.1f) / 0.1f;   // match ref op order

#pragma unroll
    for (int mi = 0; mi < 4; ++mi) {
#pragma unroll
        for (int nj = 0; nj < 2; ++nj) {
#pragma unroll
            for (int r = 0; r < 16; ++r) {
                int row = bm + wm + mi * 32 + (r & 3) + 8 * (r >> 2) + 4 * fh;
                int col = bn + wn + nj * 32 + fm;
                float y = (float)acc[mi][nj][r] * scale;
                y = rintf(y);
                y = fminf(fmaxf(y, -128.0f), 127.0f);
                out[(size_t)row * N_OUT + col] = y;
            }
        }
    }

    if (bm == 0 && bn == 0 && tid == 0)
        out[(size_t)M_TOK * N_OUT] = 0.1f;
}

// -------------------------------------------------------------------------
extern "C" void kernel_launch(void* const* d_in, const int* in_sizes, int n_in,
                              void* d_out, int out_size, void* d_ws, size_t ws_size,
                              hipStream_t stream)
{
    const int*   x_q     = (const int*)d_in[0];   // [8192*4096] int32 carriers
    const int*   w_q     = (const int*)d_in[1];   // [4096*4096] int32 carriers
    const float* scale_x = (const float*)d_in[2]; // 1 element
    float* out = (float*)d_out;

    char* A8 = (char*)d_ws;                              // 32 MB fragment-major
    char* B8 = (char*)d_ws + (size_t)M_TOK * K_IN;       // 16 MB fragment-major

    const int ntA = M_TOK * (K_IN / 16);   // 2097152 threads (16 k each)
    const int ntB = N_OUT * (K_IN / 16);   // 1048576

    pack_frag<<<(ntA + ntB) / 256, 256, 0, stream>>>(
        (const int4*)x_q, (const int4*)w_q, (int*)A8, (int*)B8, ntA, ntB);

    // 512 blocks (16 N-tiles x 32 M-tiles), 512 threads, NO LDS
    gemm_i8_kernel<<<512, 512, 0, stream>>>(A8, B8, scale_x, out);
}

// Round 10
// 452.928 us; speedup vs baseline: 1.1175x; 1.1175x over previous
//
#include <hip/hip_runtime.h>
#include <stdint.h>

typedef int v4i  __attribute__((ext_vector_type(4)));
typedef int v16i __attribute__((ext_vector_type(16)));

#define M_TOK 8192
#define N_OUT 4096
#define K_IN  4096
#define KT_N  (K_IN / 32)          // 128 fragment columns (k-steps)

#define BM 256
#define BN 256
#define BK 64                      // bytes (= i8 elems) per K-tile
#define NT (K_IN / BK)             // 64 K-tiles
#define SLOT_A 16384               // A-only ring slot: 256 rows x 64 B
#define LDS_BYTES (4 * SLOT_A)     // 64 KiB, ring of 4

// sched_group_barrier masks (LLVM SchedGroupMask, verified m137)
#define SGB __builtin_amdgcn_sched_group_barrier
#define SG_MFMA 0x8
#define SG_VMEM 0x20
#define SG_DSRD 0x100

// -------------------------------------------------------------------------
// R10: SPLIT-PIPE GEMM. Evidence: R3-R8 (LDS path) pinned at 2707 cyc/tile
// = MFMA (1171) + LDS (~1536) serial sum under five schedules; R9 (all-
// VMEM, no LDS) = worse (VMEM pipe serializes too, L2 latency exposed),
// but proved the frag-major global path is correct and SQ_LDS_BANK_CONFLICT
// is pure gload_lds write-burst cost. Neither memory pipe overlaps MFMA,
// but they are DIFFERENT pipes -- so split: A (2/3 of operand traffic)
// via LDS (gload_lds + swizzle + ds_read, the proven path), B (1/3) via
// fragment-major global loads to registers (R9 machinery). LDS demand
// drops 1536 -> ~1100 cyc/tile (reads 96->64 b128, staging 32->16
// gloads); VMEM carries 32 KB/tile vs 96 in R9 (B panel 8 KB/k-step is
// L1/L2-resident). Pessimistic serial sum: 1171+1100 = 2270 -> ~120 us;
// any VMEM overlap -> ~100 us.
// Counter check: SQ_LDS_BANK_CONFLICT must halve to ~6.3e6.
// -------------------------------------------------------------------------

__device__ __forceinline__ int pack4(int4 a) {
    return (a.x & 255) | ((a.y & 255) << 8) | ((a.z & 255) << 16) | ((a.w & 255) << 24);
}

// ---- pack: A -> linear int8 [M][K] (for swizzled gload_lds staging);
//      B -> fragment-major [N/32][KT_N][1KB] (lane-major 32x32 frags).
__global__ __launch_bounds__(256) void pack_both(
    const int4* __restrict__ x, const int4* __restrict__ w,
    int* __restrict__ dA, int* __restrict__ dB, int n4x, int ntB)
{
    int i = blockIdx.x * blockDim.x + threadIdx.x;
    if (i < n4x) {
        dA[i] = pack4(x[i]);                 // A: 16B read -> 4B packed write
    } else {
        int j = i - n4x;
        if (j >= ntB) return;
        const int r  = j >> 8;               // B row (K/16 = 256 thr/row)
        const int k0 = (j & 255) << 4;       // first k of this thread's 16
        const int4* p = w + ((size_t)r * K_IN + k0) / 4;
        int4 c0 = p[0], c1 = p[1], c2 = p[2], c3 = p[3];
        const int kt   = k0 >> 5;
        const int lane = (r & 31) + (((k0 >> 4) & 1) << 5);
        int* q = dB + ((((size_t)(r >> 5) * KT_N + kt) << 8) + (lane << 2));
        q[0] = pack4(c0); q[1] = pack4(c1); q[2] = pack4(c2); q[3] = pack4(c3);
    }
}

// -------------------------------------------------------------------------
// GEMM: 256x256 tile, BK=64, 8 waves (2Mx4N), wave = 128x64 as 4x2 of
// mfma_i32_32x32x32_i8. A: ring-4 LDS (64 KiB). B: frag-major global.
// One barrier per K-tile, vmcnt(8) boundary wait (exact analysis:
// prologue tile-0 needs <=8, steady state 12; 8 is safe everywhere, the
// over-wait only drains B-loads already needed next phase).
// -------------------------------------------------------------------------
__global__ __launch_bounds__(512, 2) void gemm_i8_kernel(
    const char* __restrict__ A8,      // [M][K] int8 row-major
    const char* __restrict__ B8,      // fragment-major [N/32][KT_N][1KB]
    const float* __restrict__ scale_ptr,
    float* __restrict__ out)          // [M][N] float + 1 scalar at end
{
    extern __shared__ char lds[];     // 4 ring slots of A: 16 KiB each

    const int tid  = threadIdx.x;
    const int wave = tid >> 6;        // 0..7
    const int lane = tid & 63;

    // ---- bijective XCD swizzle of the 512-block grid (512 % 8 == 0).
    int wg = (blockIdx.x & 7) * 64 + (blockIdx.x >> 3);
    const int bx = wg >> 5;           // 0..15 (N tiles)
    const int by = wg & 31;           // 0..31 (M tiles)
    const int bm = by * BM;
    const int bn = bx * BN;

    const int wr = wave >> 2;         // 0..1
    const int wc = wave & 3;          // 0..3
    const int wm = wr * 128;          // wave row offset in tile
    const int wn = wc * 64;           // wave col offset in tile

    v16i acc[4][2];
#pragma unroll
    for (int mi = 0; mi < 4; ++mi)
#pragma unroll
        for (int nj = 0; nj < 2; ++nj)
#pragma unroll
            for (int r = 0; r < 16; ++r)
                acc[mi][nj][r] = 0;

    // ---- A staging: wave stages rows [wave*32, +32), 2 gload_lds/tile.
    // Source granule pre-swizzled (gload_lds dest is linear lane*16):
    // f(row) = ((row>>1)&3) ^ ((row>>3)&3), row = r0 + srow.
    const int srow = lane >> 2;                                   // 0..15

    const char* gA[2]; int ldsAoff[2];
#pragma unroll
    for (int q = 0; q < 2; ++q) {
        const int r0  = wave * 32 + q * 16;
        const int f   = ((srow >> 1) & 3) ^ ((srow >> 3) & 1) ^ (q << 1);
        const int sgr = (lane & 3) ^ f;                // swizzled src granule
        gA[q] = A8 + (size_t)(bm + r0 + srow) * K_IN + sgr * 16;
        ldsAoff[q] = r0 * 64;
    }

    // ISSUE_A: dest slot (tile)&3; source K clamped (dest slot dead when
    // tile >= NT, staging stale data is harmless; keeps body branch-free).
#define ISSUE_A(tile, q) do {                                                \
        char* _rb = lds + ((tile) & 3) * SLOT_A;                             \
        const int _src = ((tile) < NT) ? (tile) : (NT - 1);                  \
        __builtin_amdgcn_global_load_lds(                                    \
            (const __attribute__((address_space(1))) void*)(gA[q] + _src * BK), \
            (__attribute__((address_space(3))) void*)(_rb + ldsAoff[q]),     \
            16, 0, 0);                                                       \
    } while (0)

    // ---- A fragment reads (32x32x32 i8): lane reads 16 B of row fm at
    // global granule g = kk*2 + fh; stored LDS granule = g ^ f(row).
    const int fm  = lane & 31;
    const int fh  = lane >> 5;                          // 0/1
    const int fsw = ((fm >> 1) & 3) ^ ((fm >> 3) & 3);  // f(row)
    const int g0  = ((0 + fh) ^ fsw) << 4;              // kk=0 byte offset
    const int g1  = ((2 + fh) ^ fsw) << 4;              // kk=1 byte offset
    const int abase = (wm + fm) * 64;                   // + mi*2048

    // ---- B fragment pointers (frag-major; include lane*16)
    const char* pB[2];
#pragma unroll
    for (int nj = 0; nj < 2; ++nj)
        pB[nj] = B8 + (((size_t)((bn + wn) / 32 + nj) * KT_N) << 10) + lane * 16;

    // ---- prologue: A tiles 0,1,2 in flight (6 gloads), tile 0 landed
    ISSUE_A(0, 0); ISSUE_A(0, 1);
    ISSUE_A(1, 0); ISSUE_A(1, 1);
    ISSUE_A(2, 0); ISSUE_A(2, 1);
    asm volatile("s_waitcnt vmcnt(4)" ::: "memory");   // A tile 0 landed
    __builtin_amdgcn_s_barrier();

    // set0 <- (tile 0, phase 0): A from LDS, B from global
    v4i a0[4], b0[2], a1[4], b1[2];
#pragma unroll
    for (int mi = 0; mi < 4; ++mi)
        a0[mi] = *(const v4i*)(lds + abase + mi * 2048 + g0);
#pragma unroll
    for (int nj = 0; nj < 2; ++nj)
        b0[nj] = *(const v4i*)(pB[nj] + 0);

    for (int t = 0; t < NT; ++t) {
        char* rb = lds + (t & 3) * SLOT_A;
        char* rn = lds + ((t + 1) & 3) * SLOT_A;
        const int ktB1 = 2 * t + 1;                                // valid
        const int ktB0 = (2 * t + 2 < 2 * NT) ? 2 * t + 2 : 2 * NT - 2; // clamp

        // ======== phase A: reads (t,ph1)->set1, stage, MFMA set0 =========
#pragma unroll
        for (int mi = 0; mi < 4; ++mi)
            a1[mi] = *(const v4i*)(rb + abase + mi * 2048 + g1);
#pragma unroll
        for (int nj = 0; nj < 2; ++nj)
            b1[nj] = *(const v4i*)(pB[nj] + (ktB1 << 10));
        ISSUE_A(t + 3, 0);
#pragma unroll
        for (int mi = 0; mi < 4; ++mi)
#pragma unroll
            for (int nj = 0; nj < 2; ++nj)
                acc[mi][nj] = __builtin_amdgcn_mfma_i32_32x32x32_i8(
                    a0[mi], b0[nj], acc[mi][nj], 0, 0, 0);
        // interleave: each MFMA-issue stall absorbs one memory issue
        SGB(SG_DSRD, 1, 0); SGB(SG_MFMA, 1, 0);
        SGB(SG_DSRD, 1, 0); SGB(SG_MFMA, 1, 0);
        SGB(SG_DSRD, 1, 0); SGB(SG_MFMA, 1, 0);
        SGB(SG_DSRD, 1, 0); SGB(SG_MFMA, 1, 0);
        SGB(SG_VMEM, 1, 0); SGB(SG_MFMA, 1, 0);
        SGB(SG_VMEM, 1, 0); SGB(SG_MFMA, 1, 0);
        SGB(SG_VMEM, 1, 0); SGB(SG_MFMA, 2, 0);

        // ---- tile boundary: counted vmcnt + ONE barrier
        ISSUE_A(t + 3, 1);
        asm volatile("s_waitcnt vmcnt(8)" ::: "memory");
        __builtin_amdgcn_s_barrier();

        // ======== phase B: reads (t+1,ph0)->set0, MFMA set1 ==============
#pragma unroll
        for (int mi = 0; mi < 4; ++mi)
            a0[mi] = *(const v4i*)(rn + abase + mi * 2048 + g0);
#pragma unroll
        for (int nj = 0; nj < 2; ++nj)
            b0[nj] = *(const v4i*)(pB[nj] + (ktB0 << 10));
#pragma unroll
        for (int mi = 0; mi < 4; ++mi)
#pragma unroll
            for (int nj = 0; nj < 2; ++nj)
                acc[mi][nj] = __builtin_amdgcn_mfma_i32_32x32x32_i8(
                    a1[mi], b1[nj], acc[mi][nj], 0, 0, 0);
        SGB(SG_DSRD, 1, 0); SGB(SG_MFMA, 1, 0);
        SGB(SG_DSRD, 1, 0); SGB(SG_MFMA, 1, 0);
        SGB(SG_DSRD, 1, 0); SGB(SG_MFMA, 1, 0);
        SGB(SG_DSRD, 1, 0); SGB(SG_MFMA, 1, 0);
        SGB(SG_VMEM, 1, 0); SGB(SG_MFMA, 1, 0);
        SGB(SG_VMEM, 1, 0); SGB(SG_MFMA, 3, 0);
    }
#undef ISSUE_A

    // ---- epilogue: y = clip(rint(acc * scale), -128, 127) as float
    // 32x32 C/D layout: col = lane&31, row = (reg&3) + 8*(reg>>2) + 4*(lane>>5)
    const float s     = scale_ptr[0];
    const float scale = (s * 0.1f) / 0.1f;   // match ref op order

#pragma unroll
    for (int mi = 0; mi < 4; ++mi) {
#pragma unroll
        for (int nj = 0; nj < 2; ++nj) {
#pragma unroll
            for (int r = 0; r < 16; ++r) {
                int row = bm + wm + mi * 32 + (r & 3) + 8 * (r >> 2) + 4 * fh;
                int col = bn + wn + nj * 32 + fm;
                float y = (float)acc[mi][nj][r] * scale;
                y = rintf(y);
                y = fminf(fmaxf(y, -128.0f), 127.0f);
                out[(size_t)row * N_OUT + col] = y;
            }
        }
    }

    if (bm == 0 && bn == 0 && tid == 0)
        out[(size_t)M_TOK * N_OUT] = 0.1f;
}

// -------------------------------------------------------------------------
extern "C" void kernel_launch(void* const* d_in, const int* in_sizes, int n_in,
                              void* d_out, int out_size, void* d_ws, size_t ws_size,
                              hipStream_t stream)
{
    const int*   x_q     = (const int*)d_in[0];   // [8192*4096] int32 carriers
    const int*   w_q     = (const int*)d_in[1];   // [4096*4096] int32 carriers
    const float* scale_x = (const float*)d_in[2]; // 1 element
    float* out = (float*)d_out;

    char* A8 = (char*)d_ws;                              // 32 MB linear int8
    char* B8 = (char*)d_ws + (size_t)M_TOK * K_IN;       // 16 MB frag-major

    const int n4x = (M_TOK * K_IN) / 4;     // 8388608 A threads
    const int ntB = N_OUT * (K_IN / 16);    // 1048576 B threads

    // one-time: allow 64 KiB dynamic LDS (host-side attribute, not a
    // stream op -> graph-capture safe)
    static bool once = []{
        hipFuncSetAttribute(reinterpret_cast<const void*>(gemm_i8_kernel),
                            hipFuncAttributeMaxDynamicSharedMemorySize,
                            LDS_BYTES);
        return true;
    }();
    (void)once;

    pack_both<<<(n4x + ntB) / 256, 256, 0, stream>>>(
        (const int4*)x_q, (const int4*)w_q, (int*)A8, (int*)B8, n4x, ntB);

    // 512 blocks (16 N-tiles x 32 M-tiles), 512 threads, 64 KiB LDS
    gemm_i8_kernel<<<512, 512, LDS_BYTES, stream>>>(A8, B8, scale_x, out);
}